// Round 5
// baseline (687.810 us; speedup 1.0000x reference)
//
#include <hip/hip_runtime.h>
#include <hip/hip_bf16.h>
#include <stdint.h>

// HydraAttention: out[b,t,d] = q[b,t,d] * Skv[b,d] / sqrt(Sqq[b,d]*Skk[b,d])
// qkv = x@W + b. B=4 T=4096 D=2048. GEMM M=16384 N=6144 K=2048, bf16 MFMA.
// Round 5: consumption-ordered A staging (q0,q2,q1,q3) + recounted waits.
// A-read phases sweep rows {0-31,128-159},{32-63,160-191},{64-95,192-223},{96-127,224-255}
// i.e. staged quarters q0,q2 feed ph1-2 and q1,q3 feed ph3-4 (wm=0/1 wave halves).

#define DMODEL 2048
#define TSEQ   4096
#define MM     16384
#define NN     6144
#define KK     2048

typedef unsigned short u16;
typedef __bf16 bf16x8 __attribute__((ext_vector_type(8)));
typedef float  f32x4  __attribute__((ext_vector_type(4)));
typedef u16    u16x8  __attribute__((ext_vector_type(8)));

__device__ __forceinline__ u16 f2bf(float f) {
    unsigned u = __float_as_uint(f);
    u += 0x7fffu + ((u >> 16) & 1u);   // RNE
    return (u16)(u >> 16);
}
__device__ __forceinline__ float bf2f(u16 h) {
    return __uint_as_float(((unsigned)h) << 16);
}

// ---------------- pass 1a: x (f32) -> xb (bf16) ----------------
__global__ void cvt_x_kernel(const float* __restrict__ x, u16* __restrict__ xb) {
    long i = ((long)blockIdx.x * 256 + threadIdx.x) * 8;
    float4 a = *(const float4*)(x + i);
    float4 b = *(const float4*)(x + i + 4);
    u16x8 o;
    o[0] = f2bf(a.x); o[1] = f2bf(a.y); o[2] = f2bf(a.z); o[3] = f2bf(a.w);
    o[4] = f2bf(b.x); o[5] = f2bf(b.y); o[6] = f2bf(b.z); o[7] = f2bf(b.w);
    *(u16x8*)(xb + i) = o;
}

// ---------------- pass 1b: W (K x N f32) -> Wt (N x K bf16) ----------------
__global__ void cvt_wt_kernel(const float* __restrict__ W, u16* __restrict__ wt) {
    __shared__ u16 tile[64][65];
    const int k0 = blockIdx.x * 64;
    const int n0 = blockIdx.y * 64;
    const int t  = threadIdx.x;
#pragma unroll
    for (int p = 0; p < 16; ++p) {
        int idx = p * 256 + t;
        int kk = idx >> 6, nn = idx & 63;
        tile[kk][nn] = f2bf(W[(long)(k0 + kk) * NN + n0 + nn]);
    }
    __syncthreads();
#pragma unroll
    for (int p = 0; p < 16; ++p) {
        int idx = p * 256 + t;
        int nn = idx >> 6, kk = idx & 63;
        wt[(long)(n0 + nn) * KK + k0 + kk] = tile[kk][nn];
    }
}

// ---------------- pass 2: 256^2-tile 8-wave pipelined bf16 MFMA GEMM ----------------
// A = xb (M x K), B = wt (N x K), both k-contiguous. 512 threads = 8 waves (2M x 4N).
// Per wave: 128x64 output = 8x4 frags of 16x16x32. LDS: 2 dbuf x (A 32K + B 32K) = 128 KiB.
// Steady state per K-tile (per-wave FIFO, oldest first; invariant entering: [Aq1,Aq3](t)):
//   ph1: rd B(t) all + A rows {0-31,128-159}; issue B0..3(t+1)          -> 6 outstanding
//   ph2: rd A {32-63,160-191}; issue Aq0,Aq2(t+1); VMW(6) drains Aq1,Aq3(t)  [3-ph slack]
//   ph3: rd A {64-95,192-223}; issue Aq1,Aq3(t+1)                       -> 8 outstanding
//   ph4: rd A {96-127,224-255}; VMW(2) drains B0..3+Aq0+Aq2(t+1)        [2-3-ph slack]
// Every VMW precedes a barrier; every ds_read's producer is drained >=1 barrier earlier.

#define BAR()   __builtin_amdgcn_s_barrier()
#define LGKM0() asm volatile("s_waitcnt lgkmcnt(0)" ::: "memory")
#define VMW(n)  asm volatile("s_waitcnt vmcnt(" #n ")" ::: "memory")
#define PRIO(x) __builtin_amdgcn_s_setprio(x)

__global__ __launch_bounds__(512, 2) void gemm_qkv_8ph(
        const u16* __restrict__ xb, const u16* __restrict__ wt,
        const float* __restrict__ bias, float* __restrict__ qout,
        u16* __restrict__ kb, u16* __restrict__ vb) {
    __shared__ u16 smem[2][2][256 * 64];   // [buf][A/B][row*64 + elem] = 128 KiB

    const int tid = threadIdx.x;
    const int l = tid & 63, w = tid >> 6;
    const int wm = w >> 2, wn = w & 3;
    const int lr = l & 15, lk = l >> 4;

    // XCD-aware bijective swizzle (nwg = 1536, 1536 % 8 == 0)
    int bid = (int)blockIdx.x;
    int swz = (bid & 7) * (1536 / 8) + (bid >> 3);
    const int m0 = (swz & 63) * 256;
    const int n0 = (swz >> 6) * 256;

    const int srow = w * 8 + (l >> 3); // staging row within a 64-row quarter
    const int sc8  = l & 7;            // staging 16B-chunk (linear LDS dest)

    f32x4 acc[8][4] = {};
    bf16x8 Bf[4][2];

#define STAGE(buf, mat, quarter, tt) do {                                              \
    int r_ = (quarter) * 64 + srow;                                                    \
    int cl_ = sc8 ^ (r_ & 7);                                                          \
    const u16* src_ = ((mat) ? wt + (long)(n0 + r_) * KK                               \
                             : xb + (long)(m0 + r_) * KK) + (tt) * 64 + cl_ * 8;       \
    __builtin_amdgcn_global_load_lds(                                                  \
        (__attribute__((address_space(1))) void*)(u16*)src_,                           \
        (__attribute__((address_space(3))) void*)&smem[buf][mat][(quarter)*4096 + w*512], \
        16, 0, 0); } while (0)

#define RD_A(dst, buf, p, i, s) do {                                                   \
    int r_ = wm * 128 + (p) * 32 + (i) * 16 + lr;                                      \
    int c_ = ((s) * 4 + lk) ^ (r_ & 7);                                                \
    dst = *(const bf16x8*)&smem[buf][0][r_ * 64 + c_ * 8]; } while (0)

#define RD_B(dst, buf, n, s) do {                                                      \
    int r_ = wn * 64 + (n) * 16 + lr;                                                  \
    int c_ = ((s) * 4 + lk) ^ (r_ & 7);                                                \
    dst = *(const bf16x8*)&smem[buf][1][r_ * 64 + c_ * 8]; } while (0)

#define MFMA_PH(p, Af)                                                                 \
    _Pragma("unroll")                                                                  \
    for (int i_ = 0; i_ < 2; ++i_) {                                                   \
        _Pragma("unroll")                                                              \
        for (int n_ = 0; n_ < 4; ++n_) {                                               \
            acc[(p)*2+i_][n_] = __builtin_amdgcn_mfma_f32_16x16x32_bf16(               \
                Af[i_][0], Bf[n_][0], acc[(p)*2+i_][n_], 0, 0, 0);                     \
            acc[(p)*2+i_][n_] = __builtin_amdgcn_mfma_f32_16x16x32_bf16(               \
                Af[i_][1], Bf[n_][1], acc[(p)*2+i_][n_], 0, 0, 0);                     \
        } }

    // prologue: stage tile 0 in consumption order; land B0..3+Aq0+Aq2.
    STAGE(0,1,0,0); STAGE(0,1,1,0); STAGE(0,1,2,0); STAGE(0,1,3,0);
    STAGE(0,0,0,0); STAGE(0,0,2,0); STAGE(0,0,1,0); STAGE(0,0,3,0);
    VMW(2); BAR();   // outstanding: [Aq1,Aq3](0) — steady-state invariant

    for (int t = 0; t < 31; ++t) {
        const int cb = t & 1, nb = cb ^ 1;
        {   // phase 1: B all (held for tile) + A p0; stage B0..3(t+1); no wait
            bf16x8 Af[2][2];
#pragma unroll
            for (int n_ = 0; n_ < 4; ++n_) { RD_B(Bf[n_][0], cb, n_, 0); RD_B(Bf[n_][1], cb, n_, 1); }
            RD_A(Af[0][0], cb, 0, 0, 0); RD_A(Af[0][1], cb, 0, 0, 1);
            RD_A(Af[1][0], cb, 0, 1, 0); RD_A(Af[1][1], cb, 0, 1, 1);
            STAGE(nb,1,0,t+1); STAGE(nb,1,1,t+1); STAGE(nb,1,2,t+1); STAGE(nb,1,3,t+1);
            BAR(); LGKM0(); PRIO(1); MFMA_PH(0, Af) PRIO(0); BAR();
        }
        {   // phase 2: A p1; stage Aq0,Aq2(t+1); VMW(6) drains Aq1,Aq3(t)
            bf16x8 Af[2][2];
            RD_A(Af[0][0], cb, 1, 0, 0); RD_A(Af[0][1], cb, 1, 0, 1);
            RD_A(Af[1][0], cb, 1, 1, 0); RD_A(Af[1][1], cb, 1, 1, 1);
            STAGE(nb,0,0,t+1); STAGE(nb,0,2,t+1);
            BAR(); LGKM0(); PRIO(1); MFMA_PH(1, Af) PRIO(0); VMW(6); BAR();
        }
        {   // phase 3: A p2 (rows 64-95/192-223, covered by ph2's VMW+BAR); stage Aq1,Aq3(t+1)
            bf16x8 Af[2][2];
            RD_A(Af[0][0], cb, 2, 0, 0); RD_A(Af[0][1], cb, 2, 0, 1);
            RD_A(Af[1][0], cb, 2, 1, 0); RD_A(Af[1][1], cb, 2, 1, 1);
            STAGE(nb,0,1,t+1); STAGE(nb,0,3,t+1);
            BAR(); LGKM0(); PRIO(1); MFMA_PH(2, Af) PRIO(0); BAR();
        }
        {   // phase 4: A p3; VMW(2) lands B0..3+Aq0+Aq2 of t+1 (issued 2-3 phases ago)
            bf16x8 Af[2][2];
            RD_A(Af[0][0], cb, 3, 0, 0); RD_A(Af[0][1], cb, 3, 0, 1);
            RD_A(Af[1][0], cb, 3, 1, 0); RD_A(Af[1][1], cb, 3, 1, 1);
            BAR(); LGKM0(); PRIO(1); MFMA_PH(3, Af) PRIO(0); VMW(2); BAR();
        }
    }
    {   // tail tile t=31 (buf 1): no staging; VMW(0) at ph2-end covers q1,q3 reads.
        bf16x8 Af[2][2];
#pragma unroll
        for (int n_ = 0; n_ < 4; ++n_) { RD_B(Bf[n_][0], 1, n_, 0); RD_B(Bf[n_][1], 1, n_, 1); }
        RD_A(Af[0][0], 1, 0, 0, 0); RD_A(Af[0][1], 1, 0, 0, 1);
        RD_A(Af[1][0], 1, 0, 1, 0); RD_A(Af[1][1], 1, 0, 1, 1);
        BAR(); LGKM0(); PRIO(1); MFMA_PH(0, Af) PRIO(0); BAR();

        RD_A(Af[0][0], 1, 1, 0, 0); RD_A(Af[0][1], 1, 1, 0, 1);
        RD_A(Af[1][0], 1, 1, 1, 0); RD_A(Af[1][1], 1, 1, 1, 1);
        BAR(); LGKM0(); PRIO(1); MFMA_PH(1, Af) PRIO(0); VMW(0); BAR();

        RD_A(Af[0][0], 1, 2, 0, 0); RD_A(Af[0][1], 1, 2, 0, 1);
        RD_A(Af[1][0], 1, 2, 1, 0); RD_A(Af[1][1], 1, 2, 1, 1);
        BAR(); LGKM0(); PRIO(1); MFMA_PH(2, Af) PRIO(0); BAR();

        RD_A(Af[0][0], 1, 3, 0, 0); RD_A(Af[0][1], 1, 3, 0, 1);
        RD_A(Af[1][0], 1, 3, 1, 0); RD_A(Af[1][1], 1, 3, 1, 1);
        LGKM0(); PRIO(1); MFMA_PH(3, Af) PRIO(0);
    }

    // epilogue: + bias, route by region. C/D: col=lane&15, row=(lane>>4)*4+reg.
    float bv[4];
#pragma unroll
    for (int n_ = 0; n_ < 4; ++n_) bv[n_] = bias[n0 + wn * 64 + n_ * 16 + lr];

#pragma unroll
    for (int mi = 0; mi < 8; ++mi) {
#pragma unroll
        for (int n_ = 0; n_ < 4; ++n_) {
            int gn = n0 + wn * 64 + n_ * 16 + lr;
#pragma unroll
            for (int j = 0; j < 4; ++j) {
                int gm = m0 + wm * 128 + mi * 16 + lk * 4 + j;
                float val = acc[mi][n_][j] + bv[n_];
                if (n0 < DMODEL) {
                    qout[(long)gm * DMODEL + gn] = val;
                } else if (n0 < 2 * DMODEL) {
                    kb[(long)gm * DMODEL + (gn - DMODEL)] = f2bf(val);
                } else {
                    vb[(long)gm * DMODEL + (gn - 2 * DMODEL)] = f2bf(val);
                }
            }
        }
    }
#undef STAGE
#undef RD_A
#undef RD_B
#undef MFMA_PH
}

// ---------------- pass 3: per-(b,d) reductions Sqq, Skk, Skv ----------------
__global__ void reduce_kernel(const float* __restrict__ q, const u16* __restrict__ kb,
                              const u16* __restrict__ vb, float* __restrict__ sums) {
    const int b  = blockIdx.x >> 7;
    const int tc = blockIdx.x & 127;
    const long row0 = (long)b * TSEQ + tc * 32;
    const int d0 = threadIdx.x * 8;
    float aqq[8] = {}, akk[8] = {}, akv[8] = {};
    for (int r = 0; r < 32; ++r) {
        long base = (row0 + r) * (long)DMODEL + d0;
        float4 q0 = *(const float4*)(q + base);
        float4 q1 = *(const float4*)(q + base + 4);
        u16x8 k8 = *(const u16x8*)(kb + base);
        u16x8 v8 = *(const u16x8*)(vb + base);
        float qa[8] = {q0.x, q0.y, q0.z, q0.w, q1.x, q1.y, q1.z, q1.w};
#pragma unroll
        for (int j = 0; j < 8; ++j) {
            float kf = bf2f(k8[j]), vf = bf2f(v8[j]);
            aqq[j] += qa[j] * qa[j];
            akk[j] += kf * kf;
            akv[j] += kf * vf;
        }
    }
    const int sbase = b * DMODEL + d0;
#pragma unroll
    for (int j = 0; j < 8; ++j) {
        atomicAdd(&sums[sbase + j],         aqq[j]);
        atomicAdd(&sums[8192 + sbase + j],  akk[j]);
        atomicAdd(&sums[16384 + sbase + j], akv[j]);
    }
}

// ---------------- pass 4: s = Skv / sqrt(Sqq*Skk) ----------------
__global__ void finalize_kernel(const float* __restrict__ sums, float* __restrict__ s) {
    int i = blockIdx.x * 256 + threadIdx.x;
    float sqq = sums[i], skk = sums[8192 + i], skv = sums[16384 + i];
    s[i] = skv / sqrtf(sqq * skk);
}

// ---------------- pass 5: out *= s[b,d] ----------------
__global__ void scale_kernel(float* __restrict__ out, const float* __restrict__ s) {
    long e = ((long)blockIdx.x * 256 + threadIdx.x) * 4;
    int d = (int)(e & (DMODEL - 1));
    int b = (int)(e >> 23);
    float4 v  = *(float4*)(out + e);
    float4 sv = *(const float4*)(s + b * DMODEL + d);
    v.x *= sv.x; v.y *= sv.y; v.z *= sv.z; v.w *= sv.w;
    *(float4*)(out + e) = v;
}

extern "C" void kernel_launch(void* const* d_in, const int* in_sizes, int n_in,
                              void* d_out, int out_size, void* d_ws, size_t ws_size,
                              hipStream_t stream) {
    const float* x    = (const float*)d_in[0];
    const float* W    = (const float*)d_in[1];
    const float* bias = (const float*)d_in[2];
    float* out = (float*)d_out;

    char* ws = (char*)d_ws;
    u16*   xb   = (u16*)(ws);                         //  64 MiB
    u16*   wt   = (u16*)(ws + 67108864L);             //  24 MiB
    u16*   kb   = (u16*)(ws + 92274688L);             //  64 MiB
    u16*   vb   = (u16*)(ws + 159383552L);            //  64 MiB
    float* sums = (float*)(ws + 226492416L);          //  96 KiB
    float* sc   = (float*)(ws + 226492416L + 98304L); //  32 KiB

    hipMemsetAsync(sums, 0, 3 * 8192 * sizeof(float), stream);
    cvt_x_kernel<<<16384, 256, 0, stream>>>(x, xb);
    cvt_wt_kernel<<<dim3(KK / 64, NN / 64), 256, 0, stream>>>(W, wt);
    gemm_qkv_8ph<<<1536, 512, 0, stream>>>(xb, wt, bias, out, kb, vb);
    reduce_kernel<<<512, 256, 0, stream>>>(out, kb, vb, sums);
    finalize_kernel<<<32, 256, 0, stream>>>(sums, sc);
    scale_kernel<<<32768, 256, 0, stream>>>(out, sc);
}

// Round 6
// 682.176 us; speedup vs baseline: 1.0083x; 1.0083x over previous
//
#include <hip/hip_runtime.h>
#include <hip/hip_bf16.h>
#include <stdint.h>

// HydraAttention: out[b,t,d] = q[b,t,d] * Skv[b,d] / sqrt(Sqq[b,d]*Skk[b,d])
// qkv = x@W + b. B=4 T=4096 D=2048. GEMM M=16384 N=6144 K=2048, bf16 MFMA.
// Round 6: hoisted addressing (ds_read offsets fold to immediates), compiler-counted
// lgkm pipelining (no explicit LGKM0), quadrant-ahead A-read ping-pong, single
// barrier + VMW(0) per K-tile, all 8 stages issued at tile start.

#define DMODEL 2048
#define TSEQ   4096
#define MM     16384
#define NN     6144
#define KK     2048

typedef unsigned short u16;
typedef __bf16 bf16x8 __attribute__((ext_vector_type(8)));
typedef float  f32x4  __attribute__((ext_vector_type(4)));
typedef u16    u16x8  __attribute__((ext_vector_type(8)));

__device__ __forceinline__ u16 f2bf(float f) {
    unsigned u = __float_as_uint(f);
    u += 0x7fffu + ((u >> 16) & 1u);   // RNE
    return (u16)(u >> 16);
}
__device__ __forceinline__ float bf2f(u16 h) {
    return __uint_as_float(((unsigned)h) << 16);
}

// ---------------- pass 1a: x (f32) -> xb (bf16) ----------------
__global__ void cvt_x_kernel(const float* __restrict__ x, u16* __restrict__ xb) {
    long i = ((long)blockIdx.x * 256 + threadIdx.x) * 8;
    float4 a = *(const float4*)(x + i);
    float4 b = *(const float4*)(x + i + 4);
    u16x8 o;
    o[0] = f2bf(a.x); o[1] = f2bf(a.y); o[2] = f2bf(a.z); o[3] = f2bf(a.w);
    o[4] = f2bf(b.x); o[5] = f2bf(b.y); o[6] = f2bf(b.z); o[7] = f2bf(b.w);
    *(u16x8*)(xb + i) = o;
}

// ---------------- pass 1b: W (K x N f32) -> Wt (N x K bf16) ----------------
__global__ void cvt_wt_kernel(const float* __restrict__ W, u16* __restrict__ wt) {
    __shared__ u16 tile[64][65];
    const int k0 = blockIdx.x * 64;
    const int n0 = blockIdx.y * 64;
    const int t  = threadIdx.x;
#pragma unroll
    for (int p = 0; p < 16; ++p) {
        int idx = p * 256 + t;
        int kk = idx >> 6, nn = idx & 63;
        tile[kk][nn] = f2bf(W[(long)(k0 + kk) * NN + n0 + nn]);
    }
    __syncthreads();
#pragma unroll
    for (int p = 0; p < 16; ++p) {
        int idx = p * 256 + t;
        int nn = idx >> 6, kk = idx & 63;
        wt[(long)(n0 + nn) * KK + k0 + kk] = tile[kk][nn];
    }
}

// ---------------- pass 2: 256^2-tile 8-wave pipelined bf16 MFMA GEMM ----------------
// A = xb (M x K), B = wt (N x K), both k-contiguous. 512 threads = 8 waves (2M x 4N).
// Per wave: 128x64 output = 8x4 frags of 16x16x32. LDS: 2 dbuf x (A 32K + B 32K) = 128 KiB.
// Per K-tile: {stage all 8 chunks of t+1 -> nb; read B+Ap0+Ap1; MFMA q0 | read Ap2;
// MFMA q1 | read Ap3; MFMA q2; MFMA q3; VMW(0); BAR}. Compiler emits counted lgkmcnt
// (reads are C++ loads) so each quadrant's LDS service hides under the previous MFMAs.
// Buffers strictly alternate per tile; each wave's reads are consumed (lgkm-drained)
// before it reaches the barrier, so one barrier per tile is sufficient.

#define BAR()   __builtin_amdgcn_s_barrier()
#define VMW(n)  asm volatile("s_waitcnt vmcnt(" #n ")" ::: "memory")
#define PRIO(x) __builtin_amdgcn_s_setprio(x)

__global__ __launch_bounds__(512, 2) void gemm_qkv_pl(
        const u16* __restrict__ xb, const u16* __restrict__ wt,
        const float* __restrict__ bias, float* __restrict__ qout,
        u16* __restrict__ kb, u16* __restrict__ vb) {
    __shared__ u16 smem[2][2][256 * 64];   // [buf][A/B][row*64 + elem] = 128 KiB

    const int tid = threadIdx.x;
    const int l = tid & 63, w = tid >> 6;
    const int wm = w >> 2, wn = w & 3;
    const int lr = l & 15, lk = l >> 4;

    // XCD-aware bijective swizzle (nwg = 1536, 1536 % 8 == 0)
    int bid = (int)blockIdx.x;
    int swz = (bid & 7) * (1536 / 8) + (bid >> 3);
    const int m0 = (swz & 63) * 256;
    const int n0 = (swz >> 6) * 256;

    const int srow = w * 8 + (l >> 3);     // staging row within a 64-row quarter
    const int sc8  = l & 7;                // staging 16B-chunk (linear LDS dest)

    // ---- hoisted addressing ----
    // Physical LDS [r][pc] holds global chunk (r, pc ^ (r&7)).  r&7 == lr&7 for all
    // read rows (wm*128, p*32, i*16 are multiples of 8), and == srow&7 for all staged
    // rows (q*64 multiple of 8) -> XORs are loop-invariant.
    const int cxor = lr & 7;
    const int aoff0 = (wm * 128 + lr) * 64 + ((0 + lk) ^ cxor) * 8;   // k-slice 0
    const int aoff1 = (wm * 128 + lr) * 64 + ((4 + lk) ^ cxor) * 8;   // k-slice 1
    const int boff0 = (wn * 64 + lr) * 64 + ((0 + lk) ^ cxor) * 8;
    const int boff1 = (wn * 64 + lr) * 64 + ((4 + lk) ^ cxor) * 8;

    const int cl = sc8 ^ (srow & 7);       // pre-swizzled global source chunk
    const u16* gA0 = xb + (long)(m0 +   0 + srow) * KK + cl * 8;
    const u16* gA1 = xb + (long)(m0 +  64 + srow) * KK + cl * 8;
    const u16* gA2 = xb + (long)(m0 + 128 + srow) * KK + cl * 8;
    const u16* gA3 = xb + (long)(m0 + 192 + srow) * KK + cl * 8;
    const u16* gB0 = wt + (long)(n0 +   0 + srow) * KK + cl * 8;
    const u16* gB1 = wt + (long)(n0 +  64 + srow) * KK + cl * 8;
    const u16* gB2 = wt + (long)(n0 + 128 + srow) * KK + cl * 8;
    const u16* gB3 = wt + (long)(n0 + 192 + srow) * KK + cl * 8;

    f32x4 acc[8][4] = {};

#define STG_(buf, mat, qq, gp) __builtin_amdgcn_global_load_lds(               \
    (__attribute__((address_space(1))) void*)(u16*)(gp),                       \
    (__attribute__((address_space(3))) void*)&smem[buf][mat][(qq)*4096 + w*512], 16, 0, 0)

#define STAGE_ALL(buf) do {                                                    \
    STG_(buf, 1, 0, gB0); STG_(buf, 1, 1, gB1);                                \
    STG_(buf, 1, 2, gB2); STG_(buf, 1, 3, gB3);                                \
    STG_(buf, 0, 0, gA0); STG_(buf, 0, 1, gA1);                                \
    STG_(buf, 0, 2, gA2); STG_(buf, 0, 3, gA3);                                \
    gA0 += 64; gA1 += 64; gA2 += 64; gA3 += 64;                                \
    gB0 += 64; gB1 += 64; gB2 += 64; gB3 += 64; } while (0)

#define RDA(dst, Ab, p) do {                                                   \
    dst[0][0] = *(const bf16x8*)(Ab + aoff0 + ((p) * 32 +  0) * 64);           \
    dst[0][1] = *(const bf16x8*)(Ab + aoff1 + ((p) * 32 +  0) * 64);           \
    dst[1][0] = *(const bf16x8*)(Ab + aoff0 + ((p) * 32 + 16) * 64);           \
    dst[1][1] = *(const bf16x8*)(Ab + aoff1 + ((p) * 32 + 16) * 64); } while (0)

#define MFMAQ(p, Af)                                                           \
    PRIO(1);                                                                   \
    _Pragma("unroll")                                                          \
    for (int i_ = 0; i_ < 2; ++i_) {                                           \
        _Pragma("unroll")                                                      \
        for (int n_ = 0; n_ < 4; ++n_) {                                       \
            acc[(p)*2+i_][n_] = __builtin_amdgcn_mfma_f32_16x16x32_bf16(       \
                Af[i_][0], Bf[n_][0], acc[(p)*2+i_][n_], 0, 0, 0);             \
            acc[(p)*2+i_][n_] = __builtin_amdgcn_mfma_f32_16x16x32_bf16(       \
                Af[i_][1], Bf[n_][1], acc[(p)*2+i_][n_], 0, 0, 0);             \
        } }                                                                    \
    PRIO(0);

#define TILE(cb, nb, en_stage) do {                                            \
    if (en_stage) STAGE_ALL(nb);                                               \
    const u16* Ab = &smem[cb][0][0];                                           \
    const u16* Bb = &smem[cb][1][0];                                           \
    bf16x8 Bf[4][2], Af0[2][2], Af1[2][2];                                     \
    _Pragma("unroll")                                                          \
    for (int n_ = 0; n_ < 4; ++n_) {                                           \
        Bf[n_][0] = *(const bf16x8*)(Bb + boff0 + n_ * 1024);                  \
        Bf[n_][1] = *(const bf16x8*)(Bb + boff1 + n_ * 1024);                  \
    }                                                                          \
    RDA(Af0, Ab, 0); RDA(Af1, Ab, 1);                                          \
    MFMAQ(0, Af0)                                                              \
    RDA(Af0, Ab, 2);                                                           \
    MFMAQ(1, Af1)                                                              \
    RDA(Af1, Ab, 3);                                                           \
    MFMAQ(2, Af0)                                                              \
    MFMAQ(3, Af1)                                                              \
    VMW(0); BAR(); } while (0)

    // prologue: stage tile 0 into buf 0, land it.
    STAGE_ALL(0);
    VMW(0); BAR();

    for (int t = 0; t < 32; t += 2) {
        TILE(0, 1, true);          // tile t   (stages t+1; t+1 <= 31 always here)
        TILE(1, 0, (t + 2 < 32));  // tile t+1 (stages t+2 unless last)
    }

    // epilogue: + bias, route by region. C/D: col=lane&15, row=(lane>>4)*4+reg.
    float bv[4];
#pragma unroll
    for (int n_ = 0; n_ < 4; ++n_) bv[n_] = bias[n0 + wn * 64 + n_ * 16 + lr];

#pragma unroll
    for (int mi = 0; mi < 8; ++mi) {
#pragma unroll
        for (int n_ = 0; n_ < 4; ++n_) {
            int gn = n0 + wn * 64 + n_ * 16 + lr;
#pragma unroll
            for (int j = 0; j < 4; ++j) {
                int gm = m0 + wm * 128 + mi * 16 + lk * 4 + j;
                float val = acc[mi][n_][j] + bv[n_];
                if (n0 < DMODEL) {
                    qout[(long)gm * DMODEL + gn] = val;
                } else if (n0 < 2 * DMODEL) {
                    kb[(long)gm * DMODEL + (gn - DMODEL)] = f2bf(val);
                } else {
                    vb[(long)gm * DMODEL + (gn - 2 * DMODEL)] = f2bf(val);
                }
            }
        }
    }
#undef STG_
#undef STAGE_ALL
#undef RDA
#undef MFMAQ
#undef TILE
}

// ---------------- pass 3: per-(b,d) reductions Sqq, Skk, Skv ----------------
__global__ void reduce_kernel(const float* __restrict__ q, const u16* __restrict__ kb,
                              const u16* __restrict__ vb, float* __restrict__ sums) {
    const int b  = blockIdx.x >> 7;
    const int tc = blockIdx.x & 127;
    const long row0 = (long)b * TSEQ + tc * 32;
    const int d0 = threadIdx.x * 8;
    float aqq[8] = {}, akk[8] = {}, akv[8] = {};
    for (int r = 0; r < 32; ++r) {
        long base = (row0 + r) * (long)DMODEL + d0;
        float4 q0 = *(const float4*)(q + base);
        float4 q1 = *(const float4*)(q + base + 4);
        u16x8 k8 = *(const u16x8*)(kb + base);
        u16x8 v8 = *(const u16x8*)(vb + base);
        float qa[8] = {q0.x, q0.y, q0.z, q0.w, q1.x, q1.y, q1.z, q1.w};
#pragma unroll
        for (int j = 0; j < 8; ++j) {
            float kf = bf2f(k8[j]), vf = bf2f(v8[j]);
            aqq[j] += qa[j] * qa[j];
            akk[j] += kf * kf;
            akv[j] += kf * vf;
        }
    }
    const int sbase = b * DMODEL + d0;
#pragma unroll
    for (int j = 0; j < 8; ++j) {
        atomicAdd(&sums[sbase + j],         aqq[j]);
        atomicAdd(&sums[8192 + sbase + j],  akk[j]);
        atomicAdd(&sums[16384 + sbase + j], akv[j]);
    }
}

// ---------------- pass 4: s = Skv / sqrt(Sqq*Skk) ----------------
__global__ void finalize_kernel(const float* __restrict__ sums, float* __restrict__ s) {
    int i = blockIdx.x * 256 + threadIdx.x;
    float sqq = sums[i], skk = sums[8192 + i], skv = sums[16384 + i];
    s[i] = skv / sqrtf(sqq * skk);
}

// ---------------- pass 5: out *= s[b,d] ----------------
__global__ void scale_kernel(float* __restrict__ out, const float* __restrict__ s) {
    long e = ((long)blockIdx.x * 256 + threadIdx.x) * 4;
    int d = (int)(e & (DMODEL - 1));
    int b = (int)(e >> 23);
    float4 v  = *(float4*)(out + e);
    float4 sv = *(const float4*)(s + b * DMODEL + d);
    v.x *= sv.x; v.y *= sv.y; v.z *= sv.z; v.w *= sv.w;
    *(float4*)(out + e) = v;
}

extern "C" void kernel_launch(void* const* d_in, const int* in_sizes, int n_in,
                              void* d_out, int out_size, void* d_ws, size_t ws_size,
                              hipStream_t stream) {
    const float* x    = (const float*)d_in[0];
    const float* W    = (const float*)d_in[1];
    const float* bias = (const float*)d_in[2];
    float* out = (float*)d_out;

    char* ws = (char*)d_ws;
    u16*   xb   = (u16*)(ws);                         //  64 MiB
    u16*   wt   = (u16*)(ws + 67108864L);             //  24 MiB
    u16*   kb   = (u16*)(ws + 92274688L);             //  64 MiB
    u16*   vb   = (u16*)(ws + 159383552L);            //  64 MiB
    float* sums = (float*)(ws + 226492416L);          //  96 KiB
    float* sc   = (float*)(ws + 226492416L + 98304L); //  32 KiB

    hipMemsetAsync(sums, 0, 3 * 8192 * sizeof(float), stream);
    cvt_x_kernel<<<16384, 256, 0, stream>>>(x, xb);
    cvt_wt_kernel<<<dim3(KK / 64, NN / 64), 256, 0, stream>>>(W, wt);
    gemm_qkv_pl<<<1536, 512, 0, stream>>>(xb, wt, bias, out, kb, vb);
    reduce_kernel<<<512, 256, 0, stream>>>(out, kb, vb, sums);
    finalize_kernel<<<32, 256, 0, stream>>>(sums, sc);
    scale_kernel<<<32768, 256, 0, stream>>>(out, sc);
}